// Round 12
// baseline (177.052 us; speedup 1.0000x reference)
//
#include <hip/hip_runtime.h>
#include <hip/hip_fp16.h>

// GraphSAGE 3-layer (mean aggr): N=50000, E=800000, 5->64->64->32.
// Round 12: k_layer1 v3 (packed fp16 x rows: one lane = one full neighbor
// row = 64 rows/wave-instruction; 8-lane group reduce; per-lane 8-output
// matvec; coalesced stores). k_fused k-loop unrolled x8 with hoisted root
// loads. CSR build via bucketed counting sort (unchanged).

#define N_NODES 50000
#define N_EDGES 800000
#define IN_C 5
#define HID_C 64
#define OUT_C 32

#define NB 196        // buckets of 256 nodes (dst >> 8)
#define BCAP 6144     // per-bucket region capacity (mean ~4096, sigma ~64)
#define BWG 256       // bucket chunks
#define BCH (N_EDGES / BWG)  // 3125 edges per chunk

typedef __attribute__((ext_vector_type(8))) short bf16x8;   // 8 bf16 = 4 VGPRs
typedef __attribute__((ext_vector_type(4))) float f32x4;    // 4 fp32 acc

__device__ __forceinline__ int rfl(int v) { return __builtin_amdgcn_readfirstlane(v); }
__device__ __forceinline__ unsigned short f2bf(float f) {  // RNE
    unsigned u = __float_as_uint(f);
    return (unsigned short)((u + 0x7fffu + ((u >> 16) & 1u)) >> 16);
}
__device__ __forceinline__ float bf2f(unsigned short b) {
    return __uint_as_float(((unsigned)b) << 16);
}
__device__ __forceinline__ float2 unpk_h2(unsigned u) {
    __half2 h = *(__half2*)&u;
    return __half22float2(h);
}

// ---------------- prep: weights bf16 hi/lo, x -> xp fp16[N,8], zero gcur ---

__global__ __launch_bounds__(256) void k_prep(
    const float* __restrict__ x,
    const float* __restrict__ W2l, const float* __restrict__ W2r,
    const float* __restrict__ W3l, const float* __restrict__ W3r,
    unsigned short* __restrict__ W2hi, unsigned short* __restrict__ W2lo,
    unsigned short* __restrict__ W3hi, unsigned short* __restrict__ W3lo,
    __half* __restrict__ xp, int* __restrict__ gcur) {
    if (blockIdx.x == 0 && threadIdx.x < NB) gcur[threadIdx.x] = 0;
    const int t = blockIdx.x * 256 + threadIdx.x;
    const int stride = gridDim.x * 256;
    for (int p = t; p < 64 * 128; p += stride) {
        int j = p >> 7, k = p & 127;
        float w = (k < 64) ? W2l[j * 64 + k] : W2r[j * 64 + (k - 64)];
        unsigned short h = f2bf(w);
        W2hi[p] = h;
        W2lo[p] = f2bf(w - bf2f(h));
    }
    for (int p = t; p < 32 * 128; p += stride) {
        int j = p >> 7, k = p & 127;
        float w = (k < 64) ? W3l[j * 64 + k] : W3r[j * 64 + (k - 64)];
        unsigned short h = f2bf(w);
        W3hi[p] = h;
        W3lo[p] = f2bf(w - bf2f(h));
    }
    for (int p = t; p < N_NODES * 8; p += stride) {
        int v = p >> 3, i = p & 7;
        xp[p] = __float2half((i < IN_C) ? x[v * IN_C + i] : 0.f);
    }
}

// ---------------- CSR build: bucketed counting sort ----------------

__global__ __launch_bounds__(256) void k_bucket(const int* __restrict__ ei,
                                                int* __restrict__ gcur,
                                                unsigned* __restrict__ ebuf) {
    __shared__ int hist[NB];
    __shared__ int loff[NB];
    __shared__ int cur[NB];
    __shared__ int gbase[NB];
    __shared__ int scanb[256];
    __shared__ unsigned stage[BCH];
    const int t = threadIdx.x;
    const int c0 = blockIdx.x * BCH;

    if (t < NB) hist[t] = 0;
    __syncthreads();
    for (int i = t; i < BCH; i += 256) {
        int d = ei[N_EDGES + c0 + i];
        atomicAdd(&hist[d >> 8], 1);
    }
    __syncthreads();
    scanb[t] = (t < NB) ? hist[t] : 0;
    __syncthreads();
#pragma unroll
    for (int o = 1; o < 256; o <<= 1) {
        int v = scanb[t];
        int a = (t >= o) ? scanb[t - o] : 0;
        __syncthreads();
        scanb[t] = v + a;
        __syncthreads();
    }
    if (t < NB) {
        int ex = (t == 0) ? 0 : scanb[t - 1];
        loff[t] = ex;
        cur[t] = ex;
        gbase[t] = atomicAdd(&gcur[t], hist[t]);
    }
    __syncthreads();
    for (int i = t; i < BCH; i += 256) {
        int d = ei[N_EDGES + c0 + i];
        int s = ei[c0 + i];
        int b = d >> 8;
        int p = atomicAdd(&cur[b], 1);
        stage[p] = ((unsigned)d << 16) | (unsigned)s;
    }
    __syncthreads();
    for (int i = t; i < BCH; i += 256) {
        unsigned ev = stage[i];
        int b = ev >> 24;
        int pos = gbase[b] + (i - loff[b]);
        if (pos < BCAP) ebuf[b * BCAP + pos] = ev;
    }
}

__global__ __launch_bounds__(256) void k_bsort(const int* __restrict__ gcur,
                                               const unsigned* __restrict__ ebuf,
                                               int* __restrict__ row_off,
                                               float* __restrict__ inv_deg,
                                               int* __restrict__ srcs) {
    __shared__ int sc[256];
    __shared__ int cnt[256];
    __shared__ int loff[256];
    __shared__ int cur[256];
    __shared__ int stage[BCAP];
    const int t = threadIdx.x;
    const int b = blockIdx.x;

    sc[t] = (t < NB) ? gcur[t] : 0;
    __syncthreads();
#pragma unroll
    for (int o = 1; o < 256; o <<= 1) {
        int v = sc[t];
        int a = (t >= o) ? sc[t - o] : 0;
        __syncthreads();
        sc[t] = v + a;
        __syncthreads();
    }
    const int base = (b == 0) ? 0 : sc[b - 1];
    const int nraw = gcur[b];
    const int n = nraw < BCAP ? nraw : BCAP;
    const int node0 = b << 8;
    const unsigned* eb = ebuf + b * BCAP;

    cnt[t] = 0;
    __syncthreads();
    for (int i = t; i < n; i += 256) atomicAdd(&cnt[(eb[i] >> 16) & 255], 1);
    __syncthreads();
    loff[t] = cnt[t];
    __syncthreads();
#pragma unroll
    for (int o = 1; o < 256; o <<= 1) {
        int v = loff[t];
        int a = (t >= o) ? loff[t - o] : 0;
        __syncthreads();
        loff[t] = v + a;
        __syncthreads();
    }
    int ex = loff[t] - cnt[t];  // exclusive
    cur[t] = ex;
    int node = node0 + t;
    if (node < N_NODES) {
        row_off[node] = base + ex;
        int d = cnt[t];
        inv_deg[node] = 1.0f / (float)(d > 1 ? d : 1);
    }
    if (b == 0 && t == 0) row_off[N_NODES] = N_EDGES;
    __syncthreads();
    for (int i = t; i < n; i += 256) {
        unsigned ev = eb[i];
        int p = atomicAdd(&cur[(ev >> 16) & 255], 1);
        stage[p] = (int)(ev & 0xFFFFu);
    }
    __syncthreads();
    for (int i = t; i < n; i += 256) srcs[base + i] = stage[i];
}

// ---------------- Layer 1: 5 -> 64, ReLU, fp16 h1 ----------------
// Wave = 8 nodes (ns=lane>>3); lane phase j=lane&7 walks neighbors j, j+8,...
// Each lane loads one FULL packed x row (uint4, 16B) -> 64 neighbor rows per
// wave instruction. 3 shfl_xor (1,2,4) x 5 channels reduce within 8-lane
// groups; per-lane 8-output matvec (outputs j*8..j*8+7); coalesced uint4
// stores (8 halves/lane, 8 lanes cover the 128B h1 row).

__global__ __launch_bounds__(256) void k_layer1(
    const __half* __restrict__ xp, const int* __restrict__ row_off,
    const int* __restrict__ srcs, const float* __restrict__ inv_deg,
    const float* __restrict__ W1l, const float* __restrict__ b1,
    const float* __restrict__ W1r, __half* __restrict__ h1) {
    const int t = threadIdx.x;
    const int lane = t & 63;
    const int ns = lane >> 3;   // node slot 0..7
    const int j = lane & 7;     // neighbor phase / output group
    const int v = blockIdx.x * 32 + (t >> 6) * 8 + ns;
    const bool valid = v < N_NODES;
    const uint4* x4 = (const uint4*)xp;

    float wl[8][IN_C], wr[8][IN_C], bb[8];
#pragma unroll
    for (int q = 0; q < 8; ++q) {
        int o = j * 8 + q;
#pragma unroll
        for (int i = 0; i < IN_C; ++i) {
            wl[q][i] = W1l[o * IN_C + i];
            wr[q][i] = W1r[o * IN_C + i];
        }
        bb[q] = b1[o];
    }

    int beg = 0, deg = 0;
    float idg = 0.f;
    if (valid) {
        beg = row_off[v];
        deg = row_off[v + 1] - beg;
        idg = inv_deg[v];
    }
    uint4 ur = valid ? x4[v] : make_uint4(0u, 0u, 0u, 0u);  // root row (hoisted)

    float a0 = 0.f, a1 = 0.f, a2 = 0.f, a3 = 0.f, a4 = 0.f;
    for (int k = j; k < deg; k += 16) {
        int i0 = srcs[beg + k];
        int k1 = k + 8;
        int i1 = (k1 < deg) ? srcs[beg + k1] : i0;
        uint4 u0 = x4[i0];
        uint4 u1 = x4[i1];
        float2 p0 = unpk_h2(u0.x), p1 = unpk_h2(u0.y), p2 = unpk_h2(u0.z);
        a0 += p0.x; a1 += p0.y; a2 += p1.x; a3 += p1.y; a4 += p2.x;
        if (k1 < deg) {
            float2 q0 = unpk_h2(u1.x), q1 = unpk_h2(u1.y), q2 = unpk_h2(u1.z);
            a0 += q0.x; a1 += q0.y; a2 += q1.x; a3 += q1.y; a4 += q2.x;
        }
    }
    // reduce across the 8-lane group (xor 1,2,4 keeps ns fixed)
#pragma unroll
    for (int msk = 1; msk < 8; msk <<= 1) {
        a0 += __shfl_xor(a0, msk, 64);
        a1 += __shfl_xor(a1, msk, 64);
        a2 += __shfl_xor(a2, msk, 64);
        a3 += __shfl_xor(a3, msk, 64);
        a4 += __shfl_xor(a4, msk, 64);
    }
    float mean[IN_C] = {a0 * idg, a1 * idg, a2 * idg, a3 * idg, a4 * idg};
    float2 r0 = unpk_h2(ur.x), r1 = unpk_h2(ur.y), r2 = unpk_h2(ur.z);
    float root[IN_C] = {r0.x, r0.y, r1.x, r1.y, r2.x};

    unsigned short res[8];
#pragma unroll
    for (int q = 0; q < 8; ++q) {
        float acc = bb[q];
#pragma unroll
        for (int i = 0; i < IN_C; ++i)
            acc += wl[q][i] * mean[i] + wr[q][i] * root[i];
        acc = fmaxf(acc, 0.f);
        res[q] = __half_as_ushort(__float2half(acc));
    }
    if (valid) {
        uint4 o;
        o.x = (unsigned)res[0] | ((unsigned)res[1] << 16);
        o.y = (unsigned)res[2] | ((unsigned)res[3] << 16);
        o.z = (unsigned)res[4] | ((unsigned)res[5] << 16);
        o.w = (unsigned)res[6] | ((unsigned)res[7] << 16);
        ((uint4*)(h1 + (size_t)v * HID_C))[j] = o;
    }
}

// ---------------- fused gather + GEMM (layers 2/3) ----------------
// Block = 4 waves = 32-node tile. Gather: lane -> (node slot ns=l>>3,
// channel group cg=l&7); lane loads uint4 (16B = 8 fp16 ch) per neighbor ->
// 8 scattered 128B rows per wave instruction. k-loop unrolled x8 (main body
// unpredicated, one predicated tail group); root row + inv_deg hoisted.
// LDS A tile bf16 hi/lo (stride 152); MFMA 16x16x32 bf16 3-product split.

template <typename T> __device__ __forceinline__ T cvt_out(float v);
template <> __device__ __forceinline__ float cvt_out<float>(float v) { return v; }
template <> __device__ __forceinline__ __half cvt_out<__half>(float v) { return __float2half(v); }

template <int DOUT, bool RELU, typename OutT>
__global__ __launch_bounds__(256) void k_fused(
    const __half* __restrict__ h, const int* __restrict__ row_off,
    const int* __restrict__ srcs, const float* __restrict__ inv_deg,
    const unsigned short* __restrict__ Whi, const unsigned short* __restrict__ Wlo,
    const float* __restrict__ bias, OutT* __restrict__ out) {
    constexpr int AP = 152;  // ushorts/row
    __shared__ __align__(16) unsigned short Ah[32][AP];
    __shared__ __align__(16) unsigned short Al[32][AP];
    const int t = threadIdx.x;
    const int lane = t & 63;
    const int w = t >> 6;
    const int ns = lane >> 3;   // node slot 0..7
    const int cg = lane & 7;    // channel group (8 halves = 16B)
    const int node0 = blockIdx.x * 32;
    const int m = w * 8 + ns;   // block-local node 0..31
    const int v = node0 + m;
    const bool valid = v < N_NODES;
    const uint4* h4 = (const uint4*)h;  // row = 8 uint4

    int beg = 0, deg = 0;
    float idg = 0.f;
    uint4 ur = make_uint4(0u, 0u, 0u, 0u);
    if (valid) {
        beg = row_off[v];
        deg = row_off[v + 1] - beg;
        idg = inv_deg[v];
        ur = h4[v * 8 + cg];  // root row chunk (hoisted; overlaps gather)
    }

    float s0 = 0.f, s1 = 0.f, s2 = 0.f, s3 = 0.f;
    float s4 = 0.f, s5 = 0.f, s6 = 0.f, s7 = 0.f;
#define ACC8(U) do {                                                \
        float2 _a = unpk_h2((U).x), _b = unpk_h2((U).y);            \
        float2 _c = unpk_h2((U).z), _d = unpk_h2((U).w);            \
        s0 += _a.x; s1 += _a.y; s2 += _b.x; s3 += _b.y;             \
        s4 += _c.x; s5 += _c.y; s6 += _d.x; s7 += _d.y;             \
    } while (0)

    const int kfull = deg & ~7;
    int k = 0;
    for (; k < kfull; k += 8) {
        int i0 = srcs[beg + k + 0];
        int i1 = srcs[beg + k + 1];
        int i2 = srcs[beg + k + 2];
        int i3 = srcs[beg + k + 3];
        int i4 = srcs[beg + k + 4];
        int i5 = srcs[beg + k + 5];
        int i6 = srcs[beg + k + 6];
        int i7 = srcs[beg + k + 7];
        uint4 u0 = h4[i0 * 8 + cg];
        uint4 u1 = h4[i1 * 8 + cg];
        uint4 u2 = h4[i2 * 8 + cg];
        uint4 u3 = h4[i3 * 8 + cg];
        uint4 u4 = h4[i4 * 8 + cg];
        uint4 u5 = h4[i5 * 8 + cg];
        uint4 u6 = h4[i6 * 8 + cg];
        uint4 u7 = h4[i7 * 8 + cg];
        ACC8(u0); ACC8(u1); ACC8(u2); ACC8(u3);
        ACC8(u4); ACC8(u5); ACC8(u6); ACC8(u7);
    }
    if (k < deg) {
        int i0 = srcs[beg + k];
        int i1 = (k + 1 < deg) ? srcs[beg + k + 1] : i0;
        int i2 = (k + 2 < deg) ? srcs[beg + k + 2] : i0;
        int i3 = (k + 3 < deg) ? srcs[beg + k + 3] : i0;
        int i4 = (k + 4 < deg) ? srcs[beg + k + 4] : i0;
        int i5 = (k + 5 < deg) ? srcs[beg + k + 5] : i0;
        int i6 = (k + 6 < deg) ? srcs[beg + k + 6] : i0;
        uint4 u0 = h4[i0 * 8 + cg];
        uint4 u1 = h4[i1 * 8 + cg];
        uint4 u2 = h4[i2 * 8 + cg];
        uint4 u3 = h4[i3 * 8 + cg];
        uint4 u4 = h4[i4 * 8 + cg];
        uint4 u5 = h4[i5 * 8 + cg];
        uint4 u6 = h4[i6 * 8 + cg];
        ACC8(u0);
        if (k + 1 < deg) ACC8(u1);
        if (k + 2 < deg) ACC8(u2);
        if (k + 3 < deg) ACC8(u3);
        if (k + 4 < deg) ACC8(u4);
        if (k + 5 < deg) ACC8(u5);
        if (k + 6 < deg) ACC8(u6);
    }
#undef ACC8

    float m0 = s0 * idg, m1 = s1 * idg, m2 = s2 * idg, m3 = s3 * idg;
    float m4 = s4 * idg, m5 = s5 * idg, m6 = s6 * idg, m7 = s7 * idg;

    {   // mean 8-channel chunk -> LDS (bf16 hi/lo)
        unsigned short a0 = f2bf(m0), a1 = f2bf(m1), a2 = f2bf(m2), a3 = f2bf(m3);
        unsigned short a4 = f2bf(m4), a5 = f2bf(m5), a6 = f2bf(m6), a7 = f2bf(m7);
        uint4 hi, lo;
        hi.x = (unsigned)a0 | ((unsigned)a1 << 16);
        hi.y = (unsigned)a2 | ((unsigned)a3 << 16);
        hi.z = (unsigned)a4 | ((unsigned)a5 << 16);
        hi.w = (unsigned)a6 | ((unsigned)a7 << 16);
        lo.x = (unsigned)f2bf(m0 - bf2f(a0)) | ((unsigned)f2bf(m1 - bf2f(a1)) << 16);
        lo.y = (unsigned)f2bf(m2 - bf2f(a2)) | ((unsigned)f2bf(m3 - bf2f(a3)) << 16);
        lo.z = (unsigned)f2bf(m4 - bf2f(a4)) | ((unsigned)f2bf(m5 - bf2f(a5)) << 16);
        lo.w = (unsigned)f2bf(m6 - bf2f(a6)) | ((unsigned)f2bf(m7 - bf2f(a7)) << 16);
        *(uint4*)&Ah[m][cg * 8] = hi;
        *(uint4*)&Al[m][cg * 8] = lo;
    }
    {   // root 8-channel chunk -> LDS
        float2 p0 = unpk_h2(ur.x), p1 = unpk_h2(ur.y);
        float2 p2 = unpk_h2(ur.z), p3 = unpk_h2(ur.w);
        unsigned short a0 = f2bf(p0.x), a1 = f2bf(p0.y), a2 = f2bf(p1.x), a3 = f2bf(p1.y);
        unsigned short a4 = f2bf(p2.x), a5 = f2bf(p2.y), a6 = f2bf(p3.x), a7 = f2bf(p3.y);
        uint4 hi, lo;
        hi.x = (unsigned)a0 | ((unsigned)a1 << 16);
        hi.y = (unsigned)a2 | ((unsigned)a3 << 16);
        hi.z = (unsigned)a4 | ((unsigned)a5 << 16);
        hi.w = (unsigned)a6 | ((unsigned)a7 << 16);
        lo.x = (unsigned)f2bf(p0.x - bf2f(a0)) | ((unsigned)f2bf(p0.y - bf2f(a1)) << 16);
        lo.y = (unsigned)f2bf(p1.x - bf2f(a2)) | ((unsigned)f2bf(p1.y - bf2f(a3)) << 16);
        lo.z = (unsigned)f2bf(p2.x - bf2f(a4)) | ((unsigned)f2bf(p2.y - bf2f(a5)) << 16);
        lo.w = (unsigned)f2bf(p3.x - bf2f(a6)) | ((unsigned)f2bf(p3.y - bf2f(a7)) << 16);
        *(uint4*)&Ah[m][64 + cg * 8] = hi;
        *(uint4*)&Al[m][64 + cg * 8] = lo;
    }
    __syncthreads();

    constexpr int CT = DOUT / 16;       // col tiles (4 or 2)
    constexpr int NTILES = 2 * CT;      // x 2 row-halves
    const int r = lane & 15;
    const int quad = lane >> 4;
#pragma unroll
    for (int ti = w; ti < NTILES; ti += 4) {
        const int n = ti % CT;
        const int rh = ti / CT;
        f32x4 acc = (f32x4){0.f, 0.f, 0.f, 0.f};
#pragma unroll
        for (int ks = 0; ks < 4; ++ks) {
            bf16x8 ah = *(const bf16x8*)&Ah[rh * 16 + r][ks * 32 + quad * 8];
            bf16x8 al = *(const bf16x8*)&Al[rh * 16 + r][ks * 32 + quad * 8];
            const size_t wb = ((size_t)(n * 16 + r)) * 128 + ks * 32 + quad * 8;
            bf16x8 bh = *(const bf16x8*)(Whi + wb);
            bf16x8 bl = *(const bf16x8*)(Wlo + wb);
            acc = __builtin_amdgcn_mfma_f32_16x16x32_bf16(ah, bh, acc, 0, 0, 0);
            acc = __builtin_amdgcn_mfma_f32_16x16x32_bf16(ah, bl, acc, 0, 0, 0);
            acc = __builtin_amdgcn_mfma_f32_16x16x32_bf16(al, bh, acc, 0, 0, 0);
        }
        float bv = bias[n * 16 + r];
#pragma unroll
        for (int g = 0; g < 4; ++g) {
            int node = node0 + rh * 16 + quad * 4 + g;
            if (node < N_NODES) {
                float vv = acc[g] + bv;
                if (RELU) vv = fmaxf(vv, 0.f);
                out[(size_t)node * DOUT + n * 16 + r] = cvt_out<OutT>(vv);
            }
        }
    }
}

// ---------------- launch ----------------

extern "C" void kernel_launch(void* const* d_in, const int* in_sizes, int n_in,
                              void* d_out, int out_size, void* d_ws, size_t ws_size,
                              hipStream_t stream) {
    const float* x   = (const float*)d_in[0];
    const int*   ei  = (const int*)d_in[1];  // [2,E]: row0=src, row1=dst
    const float* W1l = (const float*)d_in[2];
    const float* b1  = (const float*)d_in[3];
    const float* W1r = (const float*)d_in[4];
    const float* W2l = (const float*)d_in[5];
    const float* b2  = (const float*)d_in[6];
    const float* W2r = (const float*)d_in[7];
    const float* W3l = (const float*)d_in[8];
    const float* b3  = (const float*)d_in[9];
    const float* W3r = (const float*)d_in[10];

    char* ws = (char*)d_ws;
    size_t off = 0;
    auto alloc = [&](size_t bytes) -> char* {
        char* p = ws + off;
        off += (bytes + 255) & ~(size_t)255;
        return p;
    };
    int*      gcur   = (int*)alloc(NB * sizeof(int));
    int*      rowoff = (int*)alloc((N_NODES + 1) * sizeof(int));
    float*    invdeg = (float*)alloc(N_NODES * sizeof(float));
    int*      srcs   = (int*)alloc(N_EDGES * sizeof(int));
    unsigned* ebuf   = (unsigned*)alloc((size_t)NB * BCAP * sizeof(unsigned));
    __half*   xp     = (__half*)alloc((size_t)N_NODES * 8 * sizeof(__half));
    __half*   h1     = (__half*)alloc((size_t)N_NODES * HID_C * sizeof(__half));
    __half*   h2     = (__half*)alloc((size_t)N_NODES * HID_C * sizeof(__half));
    unsigned short* W2hi = (unsigned short*)alloc(64 * 128 * 2);
    unsigned short* W2lo = (unsigned short*)alloc(64 * 128 * 2);
    unsigned short* W3hi = (unsigned short*)alloc(32 * 128 * 2);
    unsigned short* W3lo = (unsigned short*)alloc(32 * 128 * 2);

    // prep (weights bf16 hi/lo + xp pack + zero gcur)
    k_prep<<<dim3(64), dim3(256), 0, stream>>>(x, W2l, W2r, W3l, W3r,
                                               W2hi, W2lo, W3hi, W3lo, xp, gcur);
    k_bucket<<<dim3(BWG), dim3(256), 0, stream>>>(ei, gcur, ebuf);
    k_bsort<<<dim3(NB), dim3(256), 0, stream>>>(gcur, ebuf, rowoff, invdeg, srcs);

    // layer 1: xp -> h1 (fp16)
    const int L1B = (N_NODES + 31) / 32;  // 1563
    k_layer1<<<dim3(L1B), dim3(256), 0, stream>>>(
        xp, rowoff, srcs, invdeg, W1l, b1, W1r, h1);

    // layer 2: fused gather+gemm, h1 -> h2 (fp16, ReLU)
    const int FT = (N_NODES + 31) / 32;  // 1563 tiles
    k_fused<HID_C, true, __half><<<dim3(FT), dim3(256), 0, stream>>>(
        h1, rowoff, srcs, invdeg, W2hi, W2lo, b2, h2);

    // layer 3: fused gather+gemm, h2 -> out (fp32)
    k_fused<OUT_C, false, float><<<dim3(FT), dim3(256), 0, stream>>>(
        h2, rowoff, srcs, invdeg, W3hi, W3lo, b3, (float*)d_out);
}

// Round 14
// 173.880 us; speedup vs baseline: 1.0182x; 1.0182x over previous
//
#include <hip/hip_runtime.h>
#include <hip/hip_fp16.h>

// GraphSAGE 3-layer (mean aggr): N=50000, E=800000, 5->64->64->32.
// Round 14 (= round 13 resubmitted after infra failure): round-11 structure
// (best measured: 172.9 us) with one retained micro-opt: k_fused hoists
// root-row + inv_deg loads ahead of the dependent gather chain. Pipeline:
//   k_prep (weights bf16 hi/lo + zero gcur) -> k_bucket -> k_bsort ->
//   k_layer1 -> k_fused<64> -> k_fused<32>.
// k_fused: 8 nodes/wave, 16B/lane dwordx4 row loads (8 scattered 128B rows
// per wave instruction), x4 unroll; MFMA 16x16x32 bf16 3-product hi/lo split.

#define N_NODES 50000
#define N_EDGES 800000
#define IN_C 5
#define HID_C 64
#define OUT_C 32

#define NB 196        // buckets of 256 nodes (dst >> 8)
#define BCAP 6144     // per-bucket region capacity (mean ~4096, sigma ~64)
#define BWG 256       // bucket chunks
#define BCH (N_EDGES / BWG)  // 3125 edges per chunk

typedef __attribute__((ext_vector_type(8))) short bf16x8;   // 8 bf16 = 4 VGPRs
typedef __attribute__((ext_vector_type(4))) float f32x4;    // 4 fp32 acc

__device__ __forceinline__ int rfl(int v) { return __builtin_amdgcn_readfirstlane(v); }
__device__ __forceinline__ float lanebc(float v, int l) {
    return __int_as_float(__builtin_amdgcn_readlane(__float_as_int(v), l));
}
__device__ __forceinline__ unsigned short f2bf(float f) {  // RNE
    unsigned u = __float_as_uint(f);
    return (unsigned short)((u + 0x7fffu + ((u >> 16) & 1u)) >> 16);
}
__device__ __forceinline__ float bf2f(unsigned short b) {
    return __uint_as_float(((unsigned)b) << 16);
}
__device__ __forceinline__ float2 unpk_h2(unsigned u) {
    __half2 h = *(__half2*)&u;
    return __half22float2(h);
}

// ---------------- weight prep: Wcat = [Wl | Wr], bf16 hi/lo; zero gcur -----

__global__ __launch_bounds__(256) void k_prep(
    const float* __restrict__ W2l, const float* __restrict__ W2r,
    const float* __restrict__ W3l, const float* __restrict__ W3r,
    unsigned short* __restrict__ W2hi, unsigned short* __restrict__ W2lo,
    unsigned short* __restrict__ W3hi, unsigned short* __restrict__ W3lo,
    int* __restrict__ gcur) {
    if (blockIdx.x == 0 && threadIdx.x < NB) gcur[threadIdx.x] = 0;
    const int t = blockIdx.x * 256 + threadIdx.x;
    const int stride = gridDim.x * 256;
    for (int p = t; p < 64 * 128; p += stride) {
        int j = p >> 7, k = p & 127;
        float w = (k < 64) ? W2l[j * 64 + k] : W2r[j * 64 + (k - 64)];
        unsigned short h = f2bf(w);
        W2hi[p] = h;
        W2lo[p] = f2bf(w - bf2f(h));
    }
    for (int p = t; p < 32 * 128; p += stride) {
        int j = p >> 7, k = p & 127;
        float w = (k < 64) ? W3l[j * 64 + k] : W3r[j * 64 + (k - 64)];
        unsigned short h = f2bf(w);
        W3hi[p] = h;
        W3lo[p] = f2bf(w - bf2f(h));
    }
}

// ---------------- CSR build: bucketed counting sort ----------------

__global__ __launch_bounds__(256) void k_bucket(const int* __restrict__ ei,
                                                int* __restrict__ gcur,
                                                unsigned* __restrict__ ebuf) {
    __shared__ int hist[NB];
    __shared__ int loff[NB];
    __shared__ int cur[NB];
    __shared__ int gbase[NB];
    __shared__ int scanb[256];
    __shared__ unsigned stage[BCH];
    const int t = threadIdx.x;
    const int c0 = blockIdx.x * BCH;

    if (t < NB) hist[t] = 0;
    __syncthreads();
    for (int i = t; i < BCH; i += 256) {
        int d = ei[N_EDGES + c0 + i];
        atomicAdd(&hist[d >> 8], 1);
    }
    __syncthreads();
    scanb[t] = (t < NB) ? hist[t] : 0;
    __syncthreads();
#pragma unroll
    for (int o = 1; o < 256; o <<= 1) {
        int v = scanb[t];
        int a = (t >= o) ? scanb[t - o] : 0;
        __syncthreads();
        scanb[t] = v + a;
        __syncthreads();
    }
    if (t < NB) {
        int ex = (t == 0) ? 0 : scanb[t - 1];
        loff[t] = ex;
        cur[t] = ex;
        gbase[t] = atomicAdd(&gcur[t], hist[t]);
    }
    __syncthreads();
    for (int i = t; i < BCH; i += 256) {
        int d = ei[N_EDGES + c0 + i];
        int s = ei[c0 + i];
        int b = d >> 8;
        int p = atomicAdd(&cur[b], 1);
        stage[p] = ((unsigned)d << 16) | (unsigned)s;
    }
    __syncthreads();
    for (int i = t; i < BCH; i += 256) {
        unsigned ev = stage[i];
        int b = ev >> 24;
        int pos = gbase[b] + (i - loff[b]);
        if (pos < BCAP) ebuf[b * BCAP + pos] = ev;
    }
}

__global__ __launch_bounds__(256) void k_bsort(const int* __restrict__ gcur,
                                               const unsigned* __restrict__ ebuf,
                                               int* __restrict__ row_off,
                                               float* __restrict__ inv_deg,
                                               int* __restrict__ srcs) {
    __shared__ int sc[256];
    __shared__ int cnt[256];
    __shared__ int loff[256];
    __shared__ int cur[256];
    __shared__ int stage[BCAP];
    const int t = threadIdx.x;
    const int b = blockIdx.x;

    sc[t] = (t < NB) ? gcur[t] : 0;
    __syncthreads();
#pragma unroll
    for (int o = 1; o < 256; o <<= 1) {
        int v = sc[t];
        int a = (t >= o) ? sc[t - o] : 0;
        __syncthreads();
        sc[t] = v + a;
        __syncthreads();
    }
    const int base = (b == 0) ? 0 : sc[b - 1];
    const int nraw = gcur[b];
    const int n = nraw < BCAP ? nraw : BCAP;
    const int node0 = b << 8;
    const unsigned* eb = ebuf + b * BCAP;

    cnt[t] = 0;
    __syncthreads();
    for (int i = t; i < n; i += 256) atomicAdd(&cnt[(eb[i] >> 16) & 255], 1);
    __syncthreads();
    loff[t] = cnt[t];
    __syncthreads();
#pragma unroll
    for (int o = 1; o < 256; o <<= 1) {
        int v = loff[t];
        int a = (t >= o) ? loff[t - o] : 0;
        __syncthreads();
        loff[t] = v + a;
        __syncthreads();
    }
    int ex = loff[t] - cnt[t];  // exclusive
    cur[t] = ex;
    int node = node0 + t;
    if (node < N_NODES) {
        row_off[node] = base + ex;
        int d = cnt[t];
        inv_deg[node] = 1.0f / (float)(d > 1 ? d : 1);
    }
    if (b == 0 && t == 0) row_off[N_NODES] = N_EDGES;
    __syncthreads();
    for (int i = t; i < n; i += 256) {
        unsigned ev = eb[i];
        int p = atomicAdd(&cur[(ev >> 16) & 255], 1);
        stage[p] = (int)(ev & 0xFFFFu);
    }
    __syncthreads();
    for (int i = t; i < n; i += 256) srcs[base + i] = stage[i];
}

// ---------------- Layer 1: 5 -> 64 fused matvec, ReLU, fp16 output ---------

__global__ __launch_bounds__(256) void k_layer1(
    const float* __restrict__ x, const int* __restrict__ row_off,
    const int* __restrict__ srcs, const float* __restrict__ inv_deg,
    const float* __restrict__ W1l, const float* __restrict__ b1,
    const float* __restrict__ W1r, __half* __restrict__ h1) {
    const int t = threadIdx.x;
    const int lane = t & 63;
    const int v = blockIdx.x * 4 + (t >> 6);
    if (v >= N_NODES) return;
    const int sub = lane >> 3;  // neighbor slot 0..7
    const int c = lane & 7;     // channel, < IN_C valid

    float wl[IN_C], wr[IN_C];
#pragma unroll
    for (int i = 0; i < IN_C; ++i) {
        wl[i] = W1l[lane * IN_C + i];
        wr[i] = W1r[lane * IN_C + i];
    }
    float bb = b1[lane];

    int beg = rfl(row_off[v]);
    int end = rfl(row_off[v + 1]);
    float sum = 0.f;
    for (int e = beg; e < end; e += 8) {
        int o = e + sub;
        if (o < end && c < IN_C) sum += x[srcs[o] * IN_C + c];
    }
    sum += __shfl_xor(sum, 8, 64);
    sum += __shfl_xor(sum, 16, 64);
    sum += __shfl_xor(sum, 32, 64);
    float summ = sum * inv_deg[v];  // lane i (i<IN_C) holds channel i
    float xv = (lane < IN_C) ? x[v * IN_C + lane] : 0.f;
    float acc = bb;
#pragma unroll
    for (int i = 0; i < IN_C; ++i) {
        acc += wl[i] * lanebc(summ, i);
        acc += wr[i] * lanebc(xv, i);
    }
    h1[v * HID_C + lane] = __float2half(fmaxf(acc, 0.f));
}

// ---------------- fused gather + GEMM (layers 2/3) ----------------
// Block = 4 waves = 32-node tile. Gather: lane -> (node slot ns=l>>3,
// channel group cg=l&7); each lane loads one uint4 (16B, 8 fp16 channels)
// per neighbor of its node -> one wave instruction fetches 8 scattered 128B
// rows (1KB). No cross-lane reduction. k-loop unrolled x4 (4 srcs + 4
// dwordx4 in flight). Root row + inv_deg hoisted before the gather chain.
// LDS A tile bf16 hi/lo (stride 152, bank-balanced); one barrier; waves
// cover 2 row-halves x DOUT/16 col-tiles of 16x16 MFMA output tiles.

template <typename T> __device__ __forceinline__ T cvt_out(float v);
template <> __device__ __forceinline__ float cvt_out<float>(float v) { return v; }
template <> __device__ __forceinline__ __half cvt_out<__half>(float v) { return __float2half(v); }

template <int DOUT, bool RELU, typename OutT>
__global__ __launch_bounds__(256) void k_fused(
    const __half* __restrict__ h, const int* __restrict__ row_off,
    const int* __restrict__ srcs, const float* __restrict__ inv_deg,
    const unsigned short* __restrict__ Whi, const unsigned short* __restrict__ Wlo,
    const float* __restrict__ bias, OutT* __restrict__ out) {
    constexpr int AP = 152;  // ushorts/row; stride 76 words = 12 mod 32 banks
    __shared__ __align__(16) unsigned short Ah[32][AP];
    __shared__ __align__(16) unsigned short Al[32][AP];
    const int t = threadIdx.x;
    const int lane = t & 63;
    const int w = t >> 6;
    const int ns = lane >> 3;   // node slot 0..7
    const int cg = lane & 7;    // channel group (8 halves = 16B)
    const int node0 = blockIdx.x * 32;
    const int m = w * 8 + ns;   // block-local node 0..31
    const int v = node0 + m;
    const bool valid = v < N_NODES;
    const uint4* h4 = (const uint4*)h;  // row = 8 uint4

    int beg = 0, deg = 0;
    float idg = 0.f;
    uint4 ur = make_uint4(0u, 0u, 0u, 0u);
    if (valid) {
        beg = row_off[v];
        deg = row_off[v + 1] - beg;
        idg = inv_deg[v];
        ur = h4[v * 8 + cg];  // root row chunk (hoisted; overlaps gather)
    }

    float s0 = 0.f, s1 = 0.f, s2 = 0.f, s3 = 0.f;
    float s4 = 0.f, s5 = 0.f, s6 = 0.f, s7 = 0.f;
    for (int k = 0; k < deg; k += 4) {
        int i0 = srcs[beg + k];
        int i1 = (k + 1 < deg) ? srcs[beg + k + 1] : i0;
        int i2 = (k + 2 < deg) ? srcs[beg + k + 2] : i0;
        int i3 = (k + 3 < deg) ? srcs[beg + k + 3] : i0;
        uint4 u0 = h4[i0 * 8 + cg];
        uint4 u1 = h4[i1 * 8 + cg];
        uint4 u2 = h4[i2 * 8 + cg];
        uint4 u3 = h4[i3 * 8 + cg];
        {
            float2 a = unpk_h2(u0.x), b = unpk_h2(u0.y);
            float2 c = unpk_h2(u0.z), d = unpk_h2(u0.w);
            s0 += a.x; s1 += a.y; s2 += b.x; s3 += b.y;
            s4 += c.x; s5 += c.y; s6 += d.x; s7 += d.y;
        }
        if (k + 1 < deg) {
            float2 a = unpk_h2(u1.x), b = unpk_h2(u1.y);
            float2 c = unpk_h2(u1.z), d = unpk_h2(u1.w);
            s0 += a.x; s1 += a.y; s2 += b.x; s3 += b.y;
            s4 += c.x; s5 += c.y; s6 += d.x; s7 += d.y;
        }
        if (k + 2 < deg) {
            float2 a = unpk_h2(u2.x), b = unpk_h2(u2.y);
            float2 c = unpk_h2(u2.z), d = unpk_h2(u2.w);
            s0 += a.x; s1 += a.y; s2 += b.x; s3 += b.y;
            s4 += c.x; s5 += c.y; s6 += d.x; s7 += d.y;
        }
        if (k + 3 < deg) {
            float2 a = unpk_h2(u3.x), b = unpk_h2(u3.y);
            float2 c = unpk_h2(u3.z), d = unpk_h2(u3.w);
            s0 += a.x; s1 += a.y; s2 += b.x; s3 += b.y;
            s4 += c.x; s5 += c.y; s6 += d.x; s7 += d.y;
        }
    }

    float m0 = s0 * idg, m1 = s1 * idg, m2 = s2 * idg, m3 = s3 * idg;
    float m4 = s4 * idg, m5 = s5 * idg, m6 = s6 * idg, m7 = s7 * idg;

    {   // mean 8-channel chunk -> LDS (bf16 hi/lo)
        unsigned short a0 = f2bf(m0), a1 = f2bf(m1), a2 = f2bf(m2), a3 = f2bf(m3);
        unsigned short a4 = f2bf(m4), a5 = f2bf(m5), a6 = f2bf(m6), a7 = f2bf(m7);
        uint4 hi, lo;
        hi.x = (unsigned)a0 | ((unsigned)a1 << 16);
        hi.y = (unsigned)a2 | ((unsigned)a3 << 16);
        hi.z = (unsigned)a4 | ((unsigned)a5 << 16);
        hi.w = (unsigned)a6 | ((unsigned)a7 << 16);
        lo.x = (unsigned)f2bf(m0 - bf2f(a0)) | ((unsigned)f2bf(m1 - bf2f(a1)) << 16);
        lo.y = (unsigned)f2bf(m2 - bf2f(a2)) | ((unsigned)f2bf(m3 - bf2f(a3)) << 16);
        lo.z = (unsigned)f2bf(m4 - bf2f(a4)) | ((unsigned)f2bf(m5 - bf2f(a5)) << 16);
        lo.w = (unsigned)f2bf(m6 - bf2f(a6)) | ((unsigned)f2bf(m7 - bf2f(a7)) << 16);
        *(uint4*)&Ah[m][cg * 8] = hi;
        *(uint4*)&Al[m][cg * 8] = lo;
    }
    {   // root 8-channel chunk -> LDS
        float2 p0 = unpk_h2(ur.x), p1 = unpk_h2(ur.y);
        float2 p2 = unpk_h2(ur.z), p3 = unpk_h2(ur.w);
        unsigned short a0 = f2bf(p0.x), a1 = f2bf(p0.y), a2 = f2bf(p1.x), a3 = f2bf(p1.y);
        unsigned short a4 = f2bf(p2.x), a5 = f2bf(p2.y), a6 = f2bf(p3.x), a7 = f2bf(p3.y);
        uint4 hi, lo;
        hi.x = (unsigned)a0 | ((unsigned)a1 << 16);
        hi.y = (unsigned)a2 | ((unsigned)a3 << 16);
        hi.z = (unsigned)a4 | ((unsigned)a5 << 16);
        hi.w = (unsigned)a6 | ((unsigned)a7 << 16);
        lo.x = (unsigned)f2bf(p0.x - bf2f(a0)) | ((unsigned)f2bf(p0.y - bf2f(a1)) << 16);
        lo.y = (unsigned)f2bf(p1.x - bf2f(a2)) | ((unsigned)f2bf(p1.y - bf2f(a3)) << 16);
        lo.z = (unsigned)f2bf(p2.x - bf2f(a4)) | ((unsigned)f2bf(p2.y - bf2f(a5)) << 16);
        lo.w = (unsigned)f2bf(p3.x - bf2f(a6)) | ((unsigned)f2bf(p3.y - bf2f(a7)) << 16);
        *(uint4*)&Ah[m][64 + cg * 8] = hi;
        *(uint4*)&Al[m][64 + cg * 8] = lo;
    }
    __syncthreads();

    constexpr int CT = DOUT / 16;       // col tiles (4 or 2)
    constexpr int NTILES = 2 * CT;      // x 2 row-halves
    const int r = lane & 15;
    const int quad = lane >> 4;
#pragma unroll
    for (int ti = w; ti < NTILES; ti += 4) {
        const int n = ti % CT;
        const int rh = ti / CT;
        f32x4 acc = (f32x4){0.f, 0.f, 0.f, 0.f};
#pragma unroll
        for (int ks = 0; ks < 4; ++ks) {
            bf16x8 ah = *(const bf16x8*)&Ah[rh * 16 + r][ks * 32 + quad * 8];
            bf16x8 al = *(const bf16x8*)&Al[rh * 16 + r][ks * 32 + quad * 8];
            const size_t wb = ((size_t)(n * 16 + r)) * 128 + ks * 32 + quad * 8;
            bf16x8 bh = *(const bf16x8*)(Whi + wb);
            bf16x8 bl = *(const bf16x8*)(Wlo + wb);
            acc = __builtin_amdgcn_mfma_f32_16x16x32_bf16(ah, bh, acc, 0, 0, 0);
            acc = __builtin_amdgcn_mfma_f32_16x16x32_bf16(ah, bl, acc, 0, 0, 0);
            acc = __builtin_amdgcn_mfma_f32_16x16x32_bf16(al, bh, acc, 0, 0, 0);
        }
        float bv = bias[n * 16 + r];
#pragma unroll
        for (int g = 0; g < 4; ++g) {
            int node = node0 + rh * 16 + quad * 4 + g;
            if (node < N_NODES) {
                float vv = acc[g] + bv;
                if (RELU) vv = fmaxf(vv, 0.f);
                out[(size_t)node * DOUT + n * 16 + r] = cvt_out<OutT>(vv);
            }
        }
    }
}

// ---------------- launch ----------------

extern "C" void kernel_launch(void* const* d_in, const int* in_sizes, int n_in,
                              void* d_out, int out_size, void* d_ws, size_t ws_size,
                              hipStream_t stream) {
    const float* x   = (const float*)d_in[0];
    const int*   ei  = (const int*)d_in[1];  // [2,E]: row0=src, row1=dst
    const float* W1l = (const float*)d_in[2];
    const float* b1  = (const float*)d_in[3];
    const float* W1r = (const float*)d_in[4];
    const float* W2l = (const float*)d_in[5];
    const float* b2  = (const float*)d_in[6];
    const float* W2r = (const float*)d_in[7];
    const float* W3l = (const float*)d_in[8];
    const float* b3  = (const float*)d_in[9];
    const float* W3r = (const float*)d_in[10];

    char* ws = (char*)d_ws;
    size_t off = 0;
    auto alloc = [&](size_t bytes) -> char* {
        char* p = ws + off;
        off += (bytes + 255) & ~(size_t)255;
        return p;
    };
    int*      gcur   = (int*)alloc(NB * sizeof(int));
    int*      rowoff = (int*)alloc((N_NODES + 1) * sizeof(int));
    float*    invdeg = (float*)alloc(N_NODES * sizeof(float));
    int*      srcs   = (int*)alloc(N_EDGES * sizeof(int));
    unsigned* ebuf   = (unsigned*)alloc((size_t)NB * BCAP * sizeof(unsigned));
    __half*   h1     = (__half*)alloc((size_t)N_NODES * HID_C * sizeof(__half));
    __half*   h2     = (__half*)alloc((size_t)N_NODES * HID_C * sizeof(__half));
    unsigned short* W2hi = (unsigned short*)alloc(64 * 128 * 2);
    unsigned short* W2lo = (unsigned short*)alloc(64 * 128 * 2);
    unsigned short* W3hi = (unsigned short*)alloc(32 * 128 * 2);
    unsigned short* W3lo = (unsigned short*)alloc(32 * 128 * 2);

    // CSR build (k_prep zeroes gcur; same-stream ordering)
    k_prep<<<dim3(48), dim3(256), 0, stream>>>(W2l, W2r, W3l, W3r,
                                               W2hi, W2lo, W3hi, W3lo, gcur);
    k_bucket<<<dim3(BWG), dim3(256), 0, stream>>>(ei, gcur, ebuf);
    k_bsort<<<dim3(NB), dim3(256), 0, stream>>>(gcur, ebuf, rowoff, invdeg, srcs);

    // layer 1 (fused matvec): x -> h1 (fp16)
    k_layer1<<<dim3(N_NODES / 4), dim3(256), 0, stream>>>(
        x, rowoff, srcs, invdeg, W1l, b1, W1r, h1);

    // layer 2: fused gather+gemm, h1 -> h2 (fp16, ReLU)
    const int FT = (N_NODES + 31) / 32;  // 1563 tiles
    k_fused<HID_C, true, __half><<<dim3(FT), dim3(256), 0, stream>>>(
        h1, rowoff, srcs, invdeg, W2hi, W2lo, b2, h2);

    // layer 3: fused gather+gemm, h2 -> out (fp32)
    k_fused<OUT_C, false, float><<<dim3(FT), dim3(256), 0, stream>>>(
        h2, rowoff, srcs, invdeg, W3hi, W3lo, b3, (float*)d_out);
}